// Round 4
// baseline (100.349 us; speedup 1.0000x reference)
//
#include <hip/hip_runtime.h>
#include <math.h>

namespace {

constexpr int NUM_NEG   = 8;
constexpr int BROWS     = 262144;
constexpr int NUM_ITEMS_C = 20000;
constexpr int M_IMP_C   = 2000;
constexpr float MARGIN1 = 0.1f;
constexpr float MARGIN2 = 0.1f;
constexpr float TAU     = 0.2f;
constexpr float EPS1    = 1e-7f;
constexpr float MAXNORM = 1.0f - 1e-5f;

// block-range dispatch: [cls | cl | rank]
constexpr int CLS_BLOCKS  = 512;
constexpr int CL_BLOCKS   = 64;
constexpr int RANK_BLOCKS = 2048;
constexpr int NBLK = CLS_BLOCKS + CL_BLOCKS + RANK_BLOCKS;
constexpr int SLOTS = 10;   // ceil(20000 / (512*4)) items per cls wave

__device__ __forceinline__ float wredsum(float v) {
    v += __shfl_xor(v, 1);  v += __shfl_xor(v, 2);  v += __shfl_xor(v, 4);
    v += __shfl_xor(v, 8);  v += __shfl_xor(v, 16); v += __shfl_xor(v, 32);
    return v;
}
__device__ __forceinline__ float wredmax(float v) {
    v = fmaxf(v, __shfl_xor(v, 1));  v = fmaxf(v, __shfl_xor(v, 2));
    v = fmaxf(v, __shfl_xor(v, 4));  v = fmaxf(v, __shfl_xor(v, 8));
    v = fmaxf(v, __shfl_xor(v, 16)); v = fmaxf(v, __shfl_xor(v, 32));
    return v;
}
__device__ __forceinline__ float ored8(float v) {   // reduce over 8-lane group
    v += __shfl_xor(v, 1); v += __shfl_xor(v, 2); v += __shfl_xor(v, 4);
    return v;
}
__device__ __forceinline__ float bcast(float v, int l) {
    return __int_as_float(__builtin_amdgcn_readlane(__float_as_int(v), l));
}
__device__ __forceinline__ float fsq(float x)  { return __builtin_amdgcn_sqrtf(x); }
__device__ __forceinline__ float frc(float x)  { return __builtin_amdgcn_rcpf(x); }
__device__ __forceinline__ float artanh_fast(float n) {
    n = fminf(n, MAXNORM);
    return 0.5f * __logf((1.f + n) * frc(1.f - n));
}
__device__ __forceinline__ float acosh_fast(float z) {
    z = fmaxf(z, 1.0f + EPS1);
    return __logf(z + fsq(fmaf(z, z, -1.0f)));
}
__device__ __forceinline__ float tanh_fast(float x) {
    const float t = __expf(2.f * x);
    return (t - 1.f) * frc(t + 1.f);
}
__device__ __forceinline__ float dot8(const float4& a0, const float4& a1,
                                      const float4& b0, const float4& b1) {
    float s0 = a0.x * b0.x + a0.y * b0.y;
    float s1 = a0.z * b0.z + a0.w * b0.w;
    float s2 = a1.x * b1.x + a1.y * b1.y;
    float s3 = a1.z * b1.z + a1.w * b1.w;
    return (s0 + s1) + (s2 + s3);
}

__global__ __launch_bounds__(256, 5) void fused_kernel(
        const float* __restrict__ emb,  const int* __restrict__ tri,
        const float* __restrict__ vtg,  const float* __restrict__ etag,
        const float* __restrict__ linw, const float* __restrict__ linb,
        const float* __restrict__ tw,   const int* __restrict__ labels,
        const int* __restrict__ imp,    float* __restrict__ part) {
    __shared__ float SA[64 * 65];   // W^T (cls ph1) -> BT (cls ph2) / TT (cl)
    __shared__ float s64[64];
    __shared__ float red4[4];
    const int tid  = threadIdx.x;
    const int lane = tid & 63, wid = tid >> 6;
    const int b    = blockIdx.x;
    float wsum = 0.f;

    if (b < CLS_BLOCKS) {
        // ================= cls loss (two-phase over one LDS array) =========
        for (int i = tid; i < 4096; i += 256) {
            const int r = i >> 6, d = i & 63;
            SA[d * 65 + r] = linw[i];              // W transposed, pitch 65
        }
        __syncthreads();
        const float bias = linb[lane];
        const float y2b  = wredsum(bias * bias);
        const int gw = b * 4 + wid, nw = CLS_BLOCKS * 4;
        // ---- phase 1: a-vectors into registers (static-indexed) ----
        float a_s[SLOTS];
        #pragma unroll
        for (int s = 0; s < SLOTS; ++s) {
            const int i = gw + s * nw;             // wave-uniform guard
            float aval = 0.f;
            if (i < NUM_ITEMS_C) {
                float x  = vtg[(long)i * 64 + lane];
                float x2 = wredsum(x * x);
                float xn = fsq(fmaxf(x2, 1e-15f));
                if (xn > MAXNORM) {                // ball_projx (wave-uniform)
                    x *= MAXNORM * frc(xn);
                    x2 = wredsum(x * x);
                    xn = fsq(fmaxf(x2, 1e-15f));
                }
                float m0 = 0.f, m1 = 0.f, m2 = 0.f, m3 = 0.f;
                #pragma unroll
                for (int d = 0; d < 64; d += 4) {
                    m0 = fmaf(bcast(x, d),     SA[(d)     * 65 + lane], m0);
                    m1 = fmaf(bcast(x, d + 1), SA[(d + 1) * 65 + lane], m1);
                    m2 = fmaf(bcast(x, d + 2), SA[(d + 2) * 65 + lane], m2);
                    m3 = fmaf(bcast(x, d + 3), SA[(d + 3) * 65 + lane], m3);
                }
                const float mx  = (m0 + m1) + (m2 + m3);
                const float mn  = fsq(fmaxf(wredsum(mx * mx), 1e-15f));
                const float g   = tanh_fast(mn * frc(xn) * artanh_fast(xn));
                const float h1  = g * frc(mn) * mx;
                const float x2h = wredsum(h1 * h1);
                const float xy  = wredsum(h1 * bias);
                const float A   = 1.f + 2.f * xy + y2b;
                const float Bc  = 1.f - x2h;
                const float den = fmaxf(1.f + 2.f * xy + x2h * y2b, 1e-15f);
                float hh = (A * h1 + Bc * bias) * frc(den);
                float hn = fsq(fmaxf(wredsum(hh * hh), 1e-15f));
                if (hn > MAXNORM) {                // ball_projx
                    hh *= MAXNORM * frc(hn);
                    hn = fsq(fmaxf(wredsum(hh * hh), 1e-15f));
                }
                aval = artanh_fast(hn) * frc(hn) * hh;   // ball_logmap0
            }
            a_s[s] = aval;
        }
        __syncthreads();
        // ---- rebuild LDS: BT = logmap0(emb_tag)^T, s64 = ||bt||^2 ----
        {
            const int j = tid >> 2, p = tid & 3;
            float e[16]; float s2 = 0.f;
            #pragma unroll
            for (int m = 0; m < 16; ++m) { e[m] = etag[j * 64 + p * 16 + m]; s2 += e[m] * e[m]; }
            s2 += __shfl_xor(s2, 1); s2 += __shfl_xor(s2, 2);
            const float n  = fsq(fmaxf(s2, 1e-15f));
            const float sc = artanh_fast(n) * frc(n);
            #pragma unroll
            for (int m = 0; m < 16; ++m) SA[(p * 16 + m) * 65 + j] = sc * e[m];
            if (p == 0) s64[j] = sc * sc * s2;
        }
        __syncthreads();
        // ---- phase 2: distances + hinge ----
        const float twl = tw[lane];
        const float b2l = s64[lane];
        float acc = 0.f;
        #pragma unroll
        for (int s = 0; s < SLOTS; ++s) {
            const int i = gw + s * nw;
            if (i < NUM_ITEMS_C) {
                const float a  = a_s[s];
                const float a2 = wredsum(a * a);
                float d0 = 0.f, d1 = 0.f, d2 = 0.f, d3 = 0.f;
                #pragma unroll
                for (int d = 0; d < 64; d += 4) {
                    d0 = fmaf(bcast(a, d),     SA[(d)     * 65 + lane], d0);
                    d1 = fmaf(bcast(a, d + 1), SA[(d + 1) * 65 + lane], d1);
                    d2 = fmaf(bcast(a, d + 2), SA[(d + 2) * 65 + lane], d2);
                    d3 = fmaf(bcast(a, d + 3), SA[(d + 3) * 65 + lane], d3);
                }
                const float dot  = (d0 + d1) + (d2 + d3);
                const float dist = fsq(fmaxf(a2 + b2l - 2.f * dot, 1e-12f));
                const float logp = __logf(dist) - twl;
                float s0 = 0.f, s1 = 0.f, s2 = 0.f, s3 = 0.f;
                #pragma unroll
                for (int k = 0; k < 64; k += 4) {
                    s0 += fmaxf(logp - bcast(logp, k)     + MARGIN1, 0.f);
                    s1 += fmaxf(logp - bcast(logp, k + 1) + MARGIN1, 0.f);
                    s2 += fmaxf(logp - bcast(logp, k + 2) + MARGIN1, 0.f);
                    s3 += fmaxf(logp - bcast(logp, k + 3) + MARGIN1, 0.f);
                }
                const float hs = (s0 + s1) + (s2 + s3);
                const float c  = (labels[(long)i * 64 + lane] > 0) ? hs : 0.f;
                acc += wredsum(c);
            }
        }
        wsum = acc;
    } else if (b < CLS_BLOCKS + CL_BLOCKS) {
        // ================= cl loss =================
        const int cb = b - CLS_BLOCKS;
        {
            const int j = tid >> 2, p = tid & 3;
            float s2 = 0.f;
            #pragma unroll
            for (int m = 0; m < 16; ++m) {
                const float e = etag[j * 64 + p * 16 + m];
                s2 += e * e;
                SA[(p * 16 + m) * 65 + j] = e;
            }
            s2 += __shfl_xor(s2, 1); s2 += __shfl_xor(s2, 2);
            if (p == 0) s64[j] = s2;
        }
        __syncthreads();
        const float y2l = s64[lane];
        const int gw = cb * 4 + wid, nw = CL_BLOCKS * 4;
        float acc = 0.f;
        for (int pI = gw; pI < M_IMP_C; pI += nw) {
            const int ai = imp[pI * 2];
            const int bi = imp[pI * 2 + 1];
            const float x2 = s64[ai];
            float c0 = 0.f, c1 = 0.f, c2 = 0.f, c3 = 0.f;
            #pragma unroll
            for (int d = 0; d < 64; d += 4) {
                c0 = fmaf(SA[(d)     * 65 + ai], SA[(d)     * 65 + lane], c0);
                c1 = fmaf(SA[(d + 1) * 65 + ai], SA[(d + 1) * 65 + lane], c1);
                c2 = fmaf(SA[(d + 2) * 65 + ai], SA[(d + 2) * 65 + lane], c2);
                c3 = fmaf(SA[(d + 3) * 65 + ai], SA[(d + 3) * 65 + lane], c3);
            }
            const float c   = (c0 + c1) + (c2 + c3);
            const float A   = 1.f - 2.f * c + y2l;
            const float Bc  = 1.f - x2;
            const float nn  = A * A * x2 - 2.f * A * Bc * c + Bc * Bc * y2l;
            const float den = fmaxf(1.f - 2.f * c + x2 * y2l, 1e-15f);
            float n = fsq(fmaxf(nn * frc(den * den), 1e-15f));
            n = fminf(n, MAXNORM);
            const float dd = __logf((1.f + n) * frc(1.f - n));   // 2*artanh(n)
            float dist = dd * dd;
            if (lane == ai) dist = 0.f;            // self-distance: ref < 1e-9 -> masked
            const float logit = (dist > 1e-9f) ? (-dist * (1.f / TAU)) : -1e30f;
            const float dp = bcast(dist, bi);
            const float lp = bcast(logit, bi);
            const float m  = wredmax(logit);
            const float se = wredsum(__expf(logit - m)) + __expf(lp - m);
            acc += m + __logf(se) + dp * (1.f / TAU);
        }
        wsum = acc;
    } else {
        // ================= rank loss: 8 lanes/row, 8 rows/wave =============
        const int rb  = b - CLS_BLOCKS - CL_BLOCKS;
        const int sub = lane & 7;                  // dim octet: dims sub*8..sub*8+7
        const int rw  = lane >> 3;                 // row within wave
        const int gwave = rb * 4 + wid;
        constexpr int STRIDE = RANK_BLOCKS * 4 * 8;
        float acc = 0.f;
        for (int row = gwave * 8 + rw; row < BROWS; row += STRIDE) {
            const int* t = tri + (long)row * 10;
            const int2 t01 = *reinterpret_cast<const int2*>(t);
            const int2 t23 = *reinterpret_cast<const int2*>(t + 2);
            const int2 t45 = *reinterpret_cast<const int2*>(t + 4);
            const int2 t67 = *reinterpret_cast<const int2*>(t + 6);
            const int2 t89 = *reinterpret_cast<const int2*>(t + 8);
            const float* ub_ = emb + (long)t01.x * 64 + sub * 8;
            const float4 ua = *reinterpret_cast<const float4*>(ub_);
            const float4 ub = *reinterpret_cast<const float4*>(ub_ + 4);
            const float* pb_ = emb + (long)t01.y * 64 + sub * 8;
            const float4 pa = *reinterpret_cast<const float4*>(pb_);
            const float4 pb = *reinterpret_cast<const float4*>(pb_ + 4);
            float dp = dot8(ua, ub, pa, pb);
            if (sub == 0) dp -= 2.f * ua.x * pa.x;   // lorentz correction
            dp = ored8(dp);
            const float dpos = acosh_fast(-dp);
            const float ps = dpos * dpos;
            // alpha: only sub==0's value is consumed (garbage elsewhere, discarded)
            const float alpha = acosh_fast(ua.x);
            const int nidx[NUM_NEG] = {t23.x, t23.y, t45.x, t45.y,
                                       t67.x, t67.y, t89.x, t89.y};
            float rs = 0.f;
            #pragma unroll
            for (int c = 0; c < 2; ++c) {
                float4 na[4], nb[4];
                #pragma unroll
                for (int k = 0; k < 4; ++k) {
                    const float* q = emb + (long)nidx[c * 4 + k] * 64 + sub * 8;
                    na[k] = *reinterpret_cast<const float4*>(q);
                    nb[k] = *reinterpret_cast<const float4*>(q + 4);
                }
                #pragma unroll
                for (int k = 0; k < 4; ++k) {
                    float dn = dot8(ua, ub, na[k], nb[k]);
                    if (sub == 0) dn -= 2.f * ua.x * na[k].x;
                    dn = ored8(dn);
                    const float dneg = acosh_fast(-dn);
                    rs += fmaxf((ps - dneg * dneg + MARGIN2) * alpha, 0.f);
                }
            }
            if (sub == 0) acc += rs;               // row-uniform; count once
        }
        wsum = wredsum(acc);
    }

    if (lane == 0) red4[wid] = wsum;
    __syncthreads();
    if (tid == 0) part[b] = red4[0] + red4[1] + red4[2] + red4[3];
}

__global__ __launch_bounds__(256) void final_reduce(
        const float* __restrict__ parts, int n, float* __restrict__ out) {
    __shared__ double red[256];
    double s = 0.0;
    for (int i = threadIdx.x; i < n; i += 256) s += (double)parts[i];
    red[threadIdx.x] = s;
    __syncthreads();
    for (int off = 128; off > 0; off >>= 1) {
        if (threadIdx.x < off) red[threadIdx.x] += red[threadIdx.x + off];
        __syncthreads();
    }
    if (threadIdx.x == 0) out[0] = (float)red[0];
}

} // namespace

extern "C" void kernel_launch(void* const* d_in, const int* in_sizes, int n_in,
                              void* d_out, int out_size, void* d_ws, size_t ws_size,
                              hipStream_t stream) {
    const float* emb    = (const float*)d_in[0];
    const float* vtg    = (const float*)d_in[1];
    const float* etag   = (const float*)d_in[2];
    const float* linw   = (const float*)d_in[3];
    const float* linb   = (const float*)d_in[4];
    const float* tw     = (const float*)d_in[5];
    const int*   tri    = (const int*)d_in[6];
    const int*   labels = (const int*)d_in[7];
    const int*   imp    = (const int*)d_in[8];
    float* parts = (float*)d_ws;

    fused_kernel<<<NBLK, 256, 0, stream>>>(emb, tri, vtg, etag, linw, linb,
                                           tw, labels, imp, parts);
    final_reduce<<<1, 256, 0, stream>>>(parts, NBLK, (float*)d_out);
}

// Round 5
// 92.759 us; speedup vs baseline: 1.0818x; 1.0818x over previous
//
#include <hip/hip_runtime.h>
#include <math.h>

namespace {

constexpr int NUM_NEG   = 8;
constexpr int BROWS     = 262144;
constexpr int NUM_ITEMS_C = 20000;
constexpr int M_IMP_C   = 2000;
constexpr float MARGIN1 = 0.1f;
constexpr float MARGIN2 = 0.1f;
constexpr float TAU     = 0.2f;
constexpr float EPS1    = 1e-7f;
constexpr float MAXNORM = 1.0f - 1e-5f;

// block-range dispatch: [cls | cl | rank]
constexpr int CLS_BLOCKS  = 512;
constexpr int CL_BLOCKS   = 64;
constexpr int RANK_BLOCKS = 2048;
constexpr int NBLK = CLS_BLOCKS + CL_BLOCKS + RANK_BLOCKS;

__device__ __forceinline__ float wredsum(float v) {
    v += __shfl_xor(v, 1);  v += __shfl_xor(v, 2);  v += __shfl_xor(v, 4);
    v += __shfl_xor(v, 8);  v += __shfl_xor(v, 16); v += __shfl_xor(v, 32);
    return v;
}
__device__ __forceinline__ float wredmax(float v) {
    v = fmaxf(v, __shfl_xor(v, 1));  v = fmaxf(v, __shfl_xor(v, 2));
    v = fmaxf(v, __shfl_xor(v, 4));  v = fmaxf(v, __shfl_xor(v, 8));
    v = fmaxf(v, __shfl_xor(v, 16)); v = fmaxf(v, __shfl_xor(v, 32));
    return v;
}
__device__ __forceinline__ float qredsum(float v) {   // 16-lane group
    v += __shfl_xor(v, 1); v += __shfl_xor(v, 2);
    v += __shfl_xor(v, 4); v += __shfl_xor(v, 8);
    return v;
}
__device__ __forceinline__ float bcast(float v, int l) {
    return __int_as_float(__builtin_amdgcn_readlane(__float_as_int(v), l));
}
__device__ __forceinline__ float fsq(float x)  { return __builtin_amdgcn_sqrtf(x); }
__device__ __forceinline__ float frc(float x)  { return __builtin_amdgcn_rcpf(x); }
__device__ __forceinline__ float artanh_fast(float n) {
    n = fminf(n, MAXNORM);
    return 0.5f * __logf((1.f + n) * frc(1.f - n));
}
__device__ __forceinline__ float acosh_fast(float z) {
    z = fmaxf(z, 1.0f + EPS1);
    return __logf(z + fsq(fmaf(z, z, -1.0f)));
}
__device__ __forceinline__ float tanh_fast(float x) {
    const float t = __expf(2.f * x);
    return (t - 1.f) * frc(t + 1.f);
}

__global__ __launch_bounds__(256) void fused_kernel(
        const float* __restrict__ emb,  const int* __restrict__ tri,
        const float* __restrict__ vtg,  const float* __restrict__ etag,
        const float* __restrict__ linw, const float* __restrict__ linb,
        const float* __restrict__ tw,   const int* __restrict__ labels,
        const int* __restrict__ imp,    float* __restrict__ part) {
    __shared__ float SA[64 * 65];   // W^T (cls ph1) -> BT (cls ph2) / TT (cl)
    __shared__ float s64[64];
    __shared__ float red4[4];
    const int tid  = threadIdx.x;
    const int lane = tid & 63, wid = tid >> 6;
    const int b    = blockIdx.x;
    float wsum = 0.f;

    if (b < CLS_BLOCKS) {
        // ================= cls loss (two-phase, one LDS array) =============
        for (int i = tid; i < 4096; i += 256) {
            const int r = i >> 6, d = i & 63;
            SA[d * 65 + r] = linw[i];              // W transposed, pitch 65
        }
        __syncthreads();
        const float bias = linb[lane];
        const float y2b  = wredsum(bias * bias);
        const int gw = b * 4 + wid, nw = CLS_BLOCKS * 4;

        // ---- phase 1: log-mapped vector a for each slot, in named regs ----
        auto phase1 = [&](int i) -> float {
            if (i >= NUM_ITEMS_C) return 0.f;      // wave-uniform guard
            float x  = vtg[(long)i * 64 + lane];
            float x2 = wredsum(x * x);
            float xn = fsq(fmaxf(x2, 1e-15f));
            if (xn > MAXNORM) {                    // ball_projx (wave-uniform)
                x *= MAXNORM * frc(xn);
                x2 = wredsum(x * x);
                xn = fsq(fmaxf(x2, 1e-15f));
            }
            float m0 = 0.f, m1 = 0.f, m2 = 0.f, m3 = 0.f;
            #pragma unroll
            for (int d = 0; d < 64; d += 4) {
                m0 = fmaf(bcast(x, d),     SA[(d)     * 65 + lane], m0);
                m1 = fmaf(bcast(x, d + 1), SA[(d + 1) * 65 + lane], m1);
                m2 = fmaf(bcast(x, d + 2), SA[(d + 2) * 65 + lane], m2);
                m3 = fmaf(bcast(x, d + 3), SA[(d + 3) * 65 + lane], m3);
            }
            const float mx  = (m0 + m1) + (m2 + m3);
            const float mn  = fsq(fmaxf(wredsum(mx * mx), 1e-15f));
            const float g   = tanh_fast(mn * frc(xn) * artanh_fast(xn));
            const float h1  = g * frc(mn) * mx;
            const float x2h = wredsum(h1 * h1);
            const float xy  = wredsum(h1 * bias);
            const float A   = 1.f + 2.f * xy + y2b;
            const float Bc  = 1.f - x2h;
            const float den = fmaxf(1.f + 2.f * xy + x2h * y2b, 1e-15f);
            float hh = (A * h1 + Bc * bias) * frc(den);
            float hn = fsq(fmaxf(wredsum(hh * hh), 1e-15f));
            if (hn > MAXNORM) {                    // ball_projx
                hh *= MAXNORM * frc(hn);
                hn = fsq(fmaxf(wredsum(hh * hh), 1e-15f));
            }
            return artanh_fast(hn) * frc(hn) * hh; // ball_logmap0
        };
        const float a0 = phase1(gw);
        const float a1 = phase1(gw + nw);
        const float a2 = phase1(gw + 2 * nw);
        const float a3 = phase1(gw + 3 * nw);
        const float a4 = phase1(gw + 4 * nw);
        const float a5 = phase1(gw + 5 * nw);
        const float a6 = phase1(gw + 6 * nw);
        const float a7 = phase1(gw + 7 * nw);
        const float a8 = phase1(gw + 8 * nw);
        const float a9 = phase1(gw + 9 * nw);
        __syncthreads();
        // ---- rebuild LDS: BT = logmap0(emb_tag)^T, s64 = ||bt||^2 ----
        {
            const int j = tid >> 2, p = tid & 3;
            float e[16]; float s2 = 0.f;
            #pragma unroll
            for (int m = 0; m < 16; ++m) { e[m] = etag[j * 64 + p * 16 + m]; s2 += e[m] * e[m]; }
            s2 += __shfl_xor(s2, 1); s2 += __shfl_xor(s2, 2);
            const float n  = fsq(fmaxf(s2, 1e-15f));
            const float sc = artanh_fast(n) * frc(n);
            #pragma unroll
            for (int m = 0; m < 16; ++m) SA[(p * 16 + m) * 65 + j] = sc * e[m];
            if (p == 0) s64[j] = sc * sc * s2;
        }
        __syncthreads();
        // ---- phase 2: distances + hinge ----
        const float twl = tw[lane];
        const float b2l = s64[lane];
        auto phase2 = [&](float a, int i) -> float {
            if (i >= NUM_ITEMS_C) return 0.f;
            const float a2v = wredsum(a * a);
            float d0 = 0.f, d1 = 0.f, d2 = 0.f, d3 = 0.f;
            #pragma unroll
            for (int d = 0; d < 64; d += 4) {
                d0 = fmaf(bcast(a, d),     SA[(d)     * 65 + lane], d0);
                d1 = fmaf(bcast(a, d + 1), SA[(d + 1) * 65 + lane], d1);
                d2 = fmaf(bcast(a, d + 2), SA[(d + 2) * 65 + lane], d2);
                d3 = fmaf(bcast(a, d + 3), SA[(d + 3) * 65 + lane], d3);
            }
            const float dot  = (d0 + d1) + (d2 + d3);
            const float dist = fsq(fmaxf(a2v + b2l - 2.f * dot, 1e-12f));
            const float logp = __logf(dist) - twl;
            float s0 = 0.f, s1 = 0.f, s2 = 0.f, s3 = 0.f;
            #pragma unroll
            for (int k = 0; k < 64; k += 4) {
                s0 += fmaxf(logp - bcast(logp, k)     + MARGIN1, 0.f);
                s1 += fmaxf(logp - bcast(logp, k + 1) + MARGIN1, 0.f);
                s2 += fmaxf(logp - bcast(logp, k + 2) + MARGIN1, 0.f);
                s3 += fmaxf(logp - bcast(logp, k + 3) + MARGIN1, 0.f);
            }
            const float hs = (s0 + s1) + (s2 + s3);
            const float c  = (labels[(long)i * 64 + lane] > 0) ? hs : 0.f;
            return wredsum(c);
        };
        float acc = 0.f;
        acc += phase2(a0, gw);
        acc += phase2(a1, gw + nw);
        acc += phase2(a2, gw + 2 * nw);
        acc += phase2(a3, gw + 3 * nw);
        acc += phase2(a4, gw + 4 * nw);
        acc += phase2(a5, gw + 5 * nw);
        acc += phase2(a6, gw + 6 * nw);
        acc += phase2(a7, gw + 7 * nw);
        acc += phase2(a8, gw + 8 * nw);
        acc += phase2(a9, gw + 9 * nw);
        wsum = acc;
    } else if (b < CLS_BLOCKS + CL_BLOCKS) {
        // ================= cl loss =================
        const int cb = b - CLS_BLOCKS;
        {
            const int j = tid >> 2, p = tid & 3;
            float s2 = 0.f;
            #pragma unroll
            for (int m = 0; m < 16; ++m) {
                const float e = etag[j * 64 + p * 16 + m];
                s2 += e * e;
                SA[(p * 16 + m) * 65 + j] = e;
            }
            s2 += __shfl_xor(s2, 1); s2 += __shfl_xor(s2, 2);
            if (p == 0) s64[j] = s2;
        }
        __syncthreads();
        const float y2l = s64[lane];
        const int gw = cb * 4 + wid, nw = CL_BLOCKS * 4;
        float acc = 0.f;
        for (int pI = gw; pI < M_IMP_C; pI += nw) {
            const int ai = imp[pI * 2];
            const int bi = imp[pI * 2 + 1];
            const float x2 = s64[ai];
            float c0 = 0.f, c1 = 0.f, c2 = 0.f, c3 = 0.f;
            #pragma unroll
            for (int d = 0; d < 64; d += 4) {
                c0 = fmaf(SA[(d)     * 65 + ai], SA[(d)     * 65 + lane], c0);
                c1 = fmaf(SA[(d + 1) * 65 + ai], SA[(d + 1) * 65 + lane], c1);
                c2 = fmaf(SA[(d + 2) * 65 + ai], SA[(d + 2) * 65 + lane], c2);
                c3 = fmaf(SA[(d + 3) * 65 + ai], SA[(d + 3) * 65 + lane], c3);
            }
            const float c   = (c0 + c1) + (c2 + c3);
            const float A   = 1.f - 2.f * c + y2l;
            const float Bc  = 1.f - x2;
            const float nn  = A * A * x2 - 2.f * A * Bc * c + Bc * Bc * y2l;
            const float den = fmaxf(1.f - 2.f * c + x2 * y2l, 1e-15f);
            float n = fsq(fmaxf(nn * frc(den * den), 1e-15f));
            n = fminf(n, MAXNORM);
            const float dd = __logf((1.f + n) * frc(1.f - n));   // 2*artanh(n)
            float dist = dd * dd;
            if (lane == ai) dist = 0.f;            // self-distance: ref < 1e-9 -> masked
            const float logit = (dist > 1e-9f) ? (-dist * (1.f / TAU)) : -1e30f;
            const float dp = bcast(dist, bi);
            const float lp = bcast(logit, bi);
            const float m  = wredmax(logit);
            const float se = wredsum(__expf(logit - m)) + __expf(lp - m);
            acc += m + __logf(se) + dp * (1.f / TAU);
        }
        wsum = acc;
    } else {
        // ========== rank loss: 16 lanes/row, 4 rows/wave (proven no-spill) =
        const int rb = b - CLS_BLOCKS - CL_BLOCKS;
        const int sub = lane & 15, quarter = lane >> 4;
        const int gwave = rb * 4 + wid;
        float acc = 0.f;
        for (int row = gwave * 4 + quarter; row < BROWS; row += RANK_BLOCKS * 16) {
            const int* t = tri + (long)row * 10;
            const int2 t01 = *reinterpret_cast<const int2*>(t);
            const int2 t23 = *reinterpret_cast<const int2*>(t + 2);
            const int2 t45 = *reinterpret_cast<const int2*>(t + 4);
            const int2 t67 = *reinterpret_cast<const int2*>(t + 6);
            const int2 t89 = *reinterpret_cast<const int2*>(t + 8);
            const int nidx[NUM_NEG] = {t23.x, t23.y, t45.x, t45.y,
                                       t67.x, t67.y, t89.x, t89.y};
            const float4 u4 = *reinterpret_cast<const float4*>(emb + (long)t01.x * 64 + sub * 4);
            const float4 p4 = *reinterpret_cast<const float4*>(emb + (long)t01.y * 64 + sub * 4);
            float4 n4[NUM_NEG];
            #pragma unroll
            for (int k = 0; k < NUM_NEG; ++k)
                n4[k] = *reinterpret_cast<const float4*>(emb + (long)nidx[k] * 64 + sub * 4);
            // lorentz inner = full_dot - 2*x0*y0
            float dp = u4.x * p4.x + u4.y * p4.y + u4.z * p4.z + u4.w * p4.w;
            if (sub == 0) dp -= 2.f * u4.x * p4.x;
            dp = qredsum(dp);
            const float dpos = acosh_fast(-dp);
            const float ps = dpos * dpos;
            const float u0 = __shfl(u4.x, lane & 48);
            const float alpha = acosh_fast(u0);
            float rs = 0.f;
            #pragma unroll
            for (int k = 0; k < NUM_NEG; ++k) {
                float dn = u4.x * n4[k].x + u4.y * n4[k].y + u4.z * n4[k].z + u4.w * n4[k].w;
                if (sub == 0) dn -= 2.f * u4.x * n4[k].x;
                dn = qredsum(dn);
                const float dneg = acosh_fast(-dn);
                rs += fmaxf((ps - dneg * dneg + MARGIN2) * alpha, 0.f);
            }
            if (sub == 0) acc += rs;               // quarter-uniform; count once
        }
        wsum = wredsum(acc);
    }

    if (lane == 0) red4[wid] = wsum;
    __syncthreads();
    if (tid == 0) part[b] = red4[0] + red4[1] + red4[2] + red4[3];
}

__global__ __launch_bounds__(256) void final_reduce(
        const float* __restrict__ parts, int n, float* __restrict__ out) {
    __shared__ double red[256];
    double s = 0.0;
    for (int i = threadIdx.x; i < n; i += 256) s += (double)parts[i];
    red[threadIdx.x] = s;
    __syncthreads();
    for (int off = 128; off > 0; off >>= 1) {
        if (threadIdx.x < off) red[threadIdx.x] += red[threadIdx.x + off];
        __syncthreads();
    }
    if (threadIdx.x == 0) out[0] = (float)red[0];
}

} // namespace

extern "C" void kernel_launch(void* const* d_in, const int* in_sizes, int n_in,
                              void* d_out, int out_size, void* d_ws, size_t ws_size,
                              hipStream_t stream) {
    const float* emb    = (const float*)d_in[0];
    const float* vtg    = (const float*)d_in[1];
    const float* etag   = (const float*)d_in[2];
    const float* linw   = (const float*)d_in[3];
    const float* linb   = (const float*)d_in[4];
    const float* tw     = (const float*)d_in[5];
    const int*   tri    = (const int*)d_in[6];
    const int*   labels = (const int*)d_in[7];
    const int*   imp    = (const int*)d_in[8];
    float* parts = (float*)d_ws;

    fused_kernel<<<NBLK, 256, 0, stream>>>(emb, tri, vtg, etag, linw, linb,
                                           tw, labels, imp, parts);
    final_reduce<<<1, 256, 0, stream>>>(parts, NBLK, (float*)d_out);
}